// Round 5
// baseline (132.169 us; speedup 1.0000x reference)
//
#include <hip/hip_runtime.h>

// Problem constants (B=2, S=512, D=128, DG=64, NG=2)
#define BQ 2
#define SQ 512
#define DQ 128
#define DGQ 64
#define NGQ 2

typedef float float2v __attribute__((ext_vector_type(2)));
typedef float float4v __attribute__((ext_vector_type(4)));
typedef _Float16 half8 __attribute__((ext_vector_type(8)));

// ws layout (floats):
//   QW1 : [B*S][128]          @ 0        (= (x@Wq)@blkdiag(W1) + b1, per group)
//   KW1 : [B*S][128]          @ 131072
//   Vp  : [B*S][NG][DG]       @ 262144   (group-major V for coalesced A@V)

// ---------------------------------------------------------------------------
// Kernel 1: fused projections (unchanged from R4 — fp32 exact).
// ---------------------------------------------------------------------------
__global__ __launch_bounds__(256) void proj_kernel(
    const float* __restrict__ x,
    const float* __restrict__ Wq, const float* __restrict__ Wk,
    const float* __restrict__ Wv,
    const float* __restrict__ W1, const float* __restrict__ b1,
    float* __restrict__ QW1, float* __restrict__ KW1, float* __restrict__ Vp)
{
    const int t = threadIdx.x;
    const int row = blockIdx.x;            // flat b*S+s, 1024 rows
    __shared__ float xs[DQ];
    __shared__ float part[3][2][DQ];
    __shared__ float qs[DQ], ks[DQ];

    if (t < DQ) xs[t] = x[(size_t)row * DQ + t];
    __syncthreads();

    const int f = t & 127, h = t >> 7;
    float aq = 0.f, ak = 0.f, av = 0.f;
    const int d0 = h * 64;
    #pragma unroll 8
    for (int d = 0; d < 64; ++d) {
        const float xv = xs[d0 + d];
        const size_t o = (size_t)(d0 + d) * DQ + f;
        aq = fmaf(xv, Wq[o], aq);
        ak = fmaf(xv, Wk[o], ak);
        av = fmaf(xv, Wv[o], av);
    }
    part[0][h][f] = aq; part[1][h][f] = ak; part[2][h][f] = av;
    __syncthreads();

    if (t < DQ) {
        qs[t] = part[0][0][t] + part[0][1][t];
        const float v = part[2][0][t] + part[2][1][t];
        Vp[((size_t)row * NGQ + (t & 1)) * DGQ + (t >> 1)] = v;
    } else {
        const int f2 = t - DQ;
        ks[f2] = part[1][0][f2] + part[1][1][f2];
    }
    __syncthreads();

    const int fb = t & 127, side = t >> 7;
    const int g = fb >> 6, c = fb & 63;
    const float* src = side ? ks : qs;
    float acc = side ? 0.f : b1[c];
    #pragma unroll 8
    for (int e = 0; e < 64; ++e)
        acc = fmaf(src[g * 64 + e], W1[e * DGQ + c], acc);
    (side ? KW1 : QW1)[(size_t)row * DQ + fb] = acc;
}

// ---------------------------------------------------------------------------
// Kernel 2: MFMA attention. One block per (b,g,i); 512 thr = 8 waves.
// W2 stage as mfma_f32_16x16x32_f16: per wave, 4 tiles of 16 keys; lane
// computes its OWN A-fragment h1 = relu(qf - kw1) in the HW A-layout
// (A[m=lane&15][k=quad*8+j]) -- no LDS transpose. B = W2 in f16 (RN),
// C init = b2 broadcast over cols. Layer 3 = 16-lane xor-shuffle reduce.
// h1->f16 RN quantization error ~1e-4 on output, threshold 6.5e-4.
// ---------------------------------------------------------------------------
__global__ __launch_bounds__(512) void attn_kernel(
    const float* __restrict__ QW1, const float* __restrict__ KW1,
    const float* __restrict__ Vp,
    const float* __restrict__ W2, const float* __restrict__ b2,
    const float* __restrict__ W3, const float* __restrict__ b3,
    const float* __restrict__ pos_add, const float* __restrict__ pos_mul,
    float* __restrict__ out)
{
    const int t = threadIdx.x;
    const int lane = t & 63, wv = t >> 6;
    const int n = lane & 15, q = lane >> 4;    // col / quad within wave
    const int i = blockIdx.x & (SQ - 1);
    const int g = (blockIdx.x >> 9) & 1;
    const int b = blockIdx.x >> 10;

    __shared__ __align__(16) float sc[SQ];
    __shared__ float redm[8], reds[8];
    __shared__ float avs[8][DGQ];

    // early prefetch: positional bias for this thread's key (coalesced)
    const size_t bo = ((size_t)g * SQ + i) * SQ + t;
    const float pmv = pos_mul[bo], pav = pos_add[bo];

    // B fragment: W2[c][o] in f16 (RN). B[k=q*8+j][n], c = kb*32 + k.
    half8 bfrag[2];
    #pragma unroll
    for (int kb = 0; kb < 2; ++kb)
        #pragma unroll
        for (int j = 0; j < 8; ++j)
            bfrag[kb][j] = (_Float16)W2[(kb * 32 + q * 8 + j) * 16 + n];

    // query channels this lane feeds: qf[kb][j] = QW1[i][g*64 + kb*32 + q*8 + j]
    const float* qrow = QW1 + ((size_t)(b * SQ + i)) * DQ + g * DGQ;
    float4 qf[4];
    #pragma unroll
    for (int kb = 0; kb < 2; ++kb) {
        qf[kb * 2 + 0] = *(const float4*)(qrow + kb * 32 + q * 8);
        qf[kb * 2 + 1] = *(const float4*)(qrow + kb * 32 + q * 8 + 4);
    }
    const float accInit = b2[n];
    const float w3n = W3[n];
    const float b3v = b3[0];

    const float* kbase = KW1 + ((size_t)(b * SQ)) * DQ + g * DGQ;

    #pragma unroll
    for (int tt = 0; tt < 4; ++tt) {
        const int m0 = wv * 64 + tt * 16;
        const float* krow = kbase + (size_t)(m0 + n) * DQ;   // A-row m = lane&15
        half8 afrag[2];
        #pragma unroll
        for (int kb = 0; kb < 2; ++kb) {
            const float4 k0 = *(const float4*)(krow + kb * 32 + q * 8);
            const float4 k1 = *(const float4*)(krow + kb * 32 + q * 8 + 4);
            const float4 q0 = qf[kb * 2], q1 = qf[kb * 2 + 1];
            afrag[kb][0] = (_Float16)fmaxf(q0.x - k0.x, 0.f);
            afrag[kb][1] = (_Float16)fmaxf(q0.y - k0.y, 0.f);
            afrag[kb][2] = (_Float16)fmaxf(q0.z - k0.z, 0.f);
            afrag[kb][3] = (_Float16)fmaxf(q0.w - k0.w, 0.f);
            afrag[kb][4] = (_Float16)fmaxf(q1.x - k1.x, 0.f);
            afrag[kb][5] = (_Float16)fmaxf(q1.y - k1.y, 0.f);
            afrag[kb][6] = (_Float16)fmaxf(q1.z - k1.z, 0.f);
            afrag[kb][7] = (_Float16)fmaxf(q1.w - k1.w, 0.f);
        }
        float4v acc = {accInit, accInit, accInit, accInit};
        acc = __builtin_amdgcn_mfma_f32_16x16x32_f16(afrag[0], bfrag[0], acc, 0, 0, 0);
        acc = __builtin_amdgcn_mfma_f32_16x16x32_f16(afrag[1], bfrag[1], acc, 0, 0, 0);

        // layer 3: lane holds h2[key=m0+q*4+r][o=n]; reduce over o (16 lanes)
        float tr0 = fmaxf(acc[0], 0.f) * w3n;
        float tr1 = fmaxf(acc[1], 0.f) * w3n;
        float tr2 = fmaxf(acc[2], 0.f) * w3n;
        float tr3 = fmaxf(acc[3], 0.f) * w3n;
        #pragma unroll
        for (int off = 1; off < 16; off <<= 1) {
            tr0 += __shfl_xor(tr0, off);
            tr1 += __shfl_xor(tr1, off);
            tr2 += __shfl_xor(tr2, off);
            tr3 += __shfl_xor(tr3, off);
        }
        if (n == 0) {
            float4 av4;
            av4.x = fmaxf(tr0 + b3v, 0.f);
            av4.y = fmaxf(tr1 + b3v, 0.f);
            av4.z = fmaxf(tr2 + b3v, 0.f);
            av4.w = fmaxf(tr3 + b3v, 0.f);
            *(float4*)&sc[m0 + q * 4] = av4;     // ds_write_b128
        }
    }
    __syncthreads();

    // ---- softmax: thread t <-> key t ----
    const float logit = fmaf(sc[t], pmv, pav);
    float m = logit;
    #pragma unroll
    for (int off = 32; off > 0; off >>= 1) m = fmaxf(m, __shfl_xor(m, off));
    if (lane == 0) redm[wv] = m;
    __syncthreads();
    float M = redm[0];
    #pragma unroll
    for (int w = 1; w < 8; ++w) M = fmaxf(M, redm[w]);
    const float e = __expf(logit - M);
    float s = e;
    #pragma unroll
    for (int off = 32; off > 0; off >>= 1) s += __shfl_xor(s, off);
    if (lane == 0) reds[wv] = s;
    sc[t] = e;                 // own slot; consumed after next barrier
    __syncthreads();
    float S = 0.f;
    #pragma unroll
    for (int w = 0; w < 8; ++w) S += reds[w];
    const float inv = 1.f / S;

    // ---- A @ V: wave wv covers keys wv*64..+63; 256B coalesced V rows ----
    const float* vbase = Vp + (((size_t)(b * SQ + wv * 64)) * NGQ + g) * DGQ + lane;
    float accv = 0.f;
    #pragma unroll 16
    for (int k = 0; k < 64; ++k)
        accv = fmaf(sc[wv * 64 + k], vbase[(size_t)k * (NGQ * DGQ)], accv);
    avs[wv][lane] = accv;
    __syncthreads();
    if (t < DGQ) {
        float sum = 0.f;
        #pragma unroll
        for (int w = 0; w < 8; ++w) sum += avs[w][t];
        out[((size_t)(b * SQ + i)) * DQ + t * NGQ + g] = sum * inv;
    }
}

extern "C" void kernel_launch(void* const* d_in, const int* in_sizes, int n_in,
                              void* d_out, int out_size, void* d_ws, size_t ws_size,
                              hipStream_t stream) {
    const float* x       = (const float*)d_in[0];
    const float* pos_add = (const float*)d_in[1];
    const float* pos_mul = (const float*)d_in[2];
    const float* Wq      = (const float*)d_in[3];
    const float* Wk      = (const float*)d_in[4];
    const float* Wv      = (const float*)d_in[5];
    const float* W1      = (const float*)d_in[6];
    const float* b1      = (const float*)d_in[7];
    const float* W2      = (const float*)d_in[8];
    const float* b2      = (const float*)d_in[9];
    const float* W3      = (const float*)d_in[10];
    const float* b3      = (const float*)d_in[11];
    float* out = (float*)d_out;

    float* ws  = (float*)d_ws;
    float* QW1 = ws;
    float* KW1 = ws + 131072;
    float* Vp  = ws + 262144;

    proj_kernel<<<BQ * SQ, 256, 0, stream>>>(x, Wq, Wk, Wv, W1, b1,
                                             QW1, KW1, Vp);
    attn_kernel<<<BQ * NGQ * SQ, 512, 0, stream>>>(QW1, KW1, Vp, W2, b2,
                                                   W3, b3, pos_add, pos_mul,
                                                   out);
}

// Round 6
// 120.637 us; speedup vs baseline: 1.0956x; 1.0956x over previous
//
#include <hip/hip_runtime.h>

// Problem constants (B=2, S=512, D=128, DG=64, NG=2)
#define BQ 2
#define SQ 512
#define DQ 128
#define DGQ 64
#define NGQ 2

typedef float float2v __attribute__((ext_vector_type(2)));

// ws layout (floats):
//   QW1 : [B*S][128]          @ 0        (= (x@Wq)@blkdiag(W1) + b1, per group)
//   KW1 : [B*S][128]          @ 131072
//   Vp  : [B*S][NG][DG]       @ 262144   (group-major V for coalesced A@V)

// ---------------------------------------------------------------------------
// Kernel 1: fused projections (unchanged — fp32 exact).
// ---------------------------------------------------------------------------
__global__ __launch_bounds__(256) void proj_kernel(
    const float* __restrict__ x,
    const float* __restrict__ Wq, const float* __restrict__ Wk,
    const float* __restrict__ Wv,
    const float* __restrict__ W1, const float* __restrict__ b1,
    float* __restrict__ QW1, float* __restrict__ KW1, float* __restrict__ Vp)
{
    const int t = threadIdx.x;
    const int row = blockIdx.x;            // flat b*S+s, 1024 rows
    __shared__ float xs[DQ];
    __shared__ float part[3][2][DQ];
    __shared__ float qs[DQ], ks[DQ];

    if (t < DQ) xs[t] = x[(size_t)row * DQ + t];
    __syncthreads();

    const int f = t & 127, h = t >> 7;
    float aq = 0.f, ak = 0.f, av = 0.f;
    const int d0 = h * 64;
    #pragma unroll 8
    for (int d = 0; d < 64; ++d) {
        const float xv = xs[d0 + d];
        const size_t o = (size_t)(d0 + d) * DQ + f;
        aq = fmaf(xv, Wq[o], aq);
        ak = fmaf(xv, Wk[o], ak);
        av = fmaf(xv, Wv[o], av);
    }
    part[0][h][f] = aq; part[1][h][f] = ak; part[2][h][f] = av;
    __syncthreads();

    if (t < DQ) {
        qs[t] = part[0][0][t] + part[0][1][t];
        const float v = part[2][0][t] + part[2][1][t];
        Vp[((size_t)row * NGQ + (t & 1)) * DGQ + (t >> 1)] = v;
    } else {
        const int f2 = t - DQ;
        ks[f2] = part[1][0][f2] + part[1][1][f2];
    }
    __syncthreads();

    const int fb = t & 127, side = t >> 7;
    const int g = fb >> 6, c = fb & 63;
    const float* src = side ? ks : qs;
    float acc = side ? 0.f : b1[c];
    #pragma unroll 8
    for (int e = 0; e < 64; ++e)
        acc = fmaf(src[g * 64 + e], W1[e * DGQ + c], acc);
    (side ? KW1 : QW1)[(size_t)row * DQ + fb] = acc;
}

// ---------------------------------------------------------------------------
// Kernel 2: one block per (b, g, 4-query tile); 512 thr, thread t = key j.
// FOUR queries per block: every krow float4, every W2 SGPR load, and every
// V element feeds 4 logit rows. 144 pk-ops per c4 between dependent loads
// covers L2 latency even at 2 blocks/CU (16 waves). MFMA abandoned (R5:
// MfmaUtil 1.6% — h1 elementwise gen dominates; wrong tool at N=16).
// __launch_bounds__(512,4): 4 waves/EU min -> VGPR capped at 128.
// ---------------------------------------------------------------------------
__global__ __launch_bounds__(512, 4) void attn_kernel(
    const float* __restrict__ QW1, const float* __restrict__ KW1,
    const float* __restrict__ Vp,
    const float* __restrict__ W2, const float* __restrict__ b2,
    const float* __restrict__ W3, const float* __restrict__ b3,
    const float* __restrict__ pos_add, const float* __restrict__ pos_mul,
    float* __restrict__ out)
{
    const int t = threadIdx.x;                  // key index j
    const int itile = blockIdx.x & 127;
    const int g = (blockIdx.x >> 7) & 1;
    const int b = blockIdx.x >> 8;
    const int i0 = itile * 4;
    const int lane = t & 63, wv = t >> 6;

    __shared__ __align__(16) float qsl[4][DGQ];     // 4 query rows (group slice)
    __shared__ __align__(16) float sc4[SQ][4];      // exp(logit) per key x query
    __shared__ float redm[4][8], reds[4][8];
    __shared__ float avs[4][8][DGQ];

    if (t < 4 * DGQ) {
        const int qq = t >> 6, e = t & 63;
        qsl[qq][e] = QW1[((size_t)(b * SQ + i0 + qq)) * DQ + g * DGQ + e];
    }
    // positional bias prefetch (shape [1,NG,1,S,S] — no batch dim)
    float pmv[4], pav[4];
    #pragma unroll
    for (int qq = 0; qq < 4; ++qq) {
        const size_t bo = ((size_t)g * SQ + i0 + qq) * SQ + t;
        pmv[qq] = pos_mul[bo];
        pav[qq] = pos_add[bo];
    }
    __syncthreads();

    const float4* krow = reinterpret_cast<const float4*>(
        KW1 + ((size_t)(b * SQ + t)) * DQ + g * DGQ);
    const float2v* b2v = reinterpret_cast<const float2v*>(b2);
    const float2v zero2 = {0.f, 0.f};

    float2v acc[4][8];
    #pragma unroll
    for (int qq = 0; qq < 4; ++qq)
        #pragma unroll
        for (int o = 0; o < 8; ++o) acc[qq][o] = b2v[o];

    float4 kva = krow[0], kvb = krow[1];
    #pragma unroll
    for (int grp = 0; grp < 8; ++grp) {
        float4 nka, nkb;
        if (grp < 7) { nka = krow[grp * 2 + 2]; nkb = krow[grp * 2 + 3]; }
        #pragma unroll
        for (int u = 0; u < 2; ++u) {
            const int c4 = grp * 2 + u;
            const float4 kv = u ? kvb : kva;
            const float2v k01 = {kv.x, kv.y}, k23 = {kv.z, kv.w};
            // h1 for all 4 queries of this 4-channel slice (16 pk ops)
            float2v h01[4], h23[4];
            #pragma unroll
            for (int qq = 0; qq < 4; ++qq) {
                const float4 qa = reinterpret_cast<const float4*>(
                    &qsl[qq][0])[c4];                     // ds_read_b128
                h01[qq] = __builtin_elementwise_max(
                    float2v{qa.x, qa.y} - k01, zero2);    // v_pk_max
                h23[qq] = __builtin_elementwise_max(
                    float2v{qa.z, qa.w} - k23, zero2);
            }
            const float2v* w2r = reinterpret_cast<const float2v*>(W2 + c4 * 64);
            #pragma unroll
            for (int o = 0; o < 8; ++o) {
                const float2v w0 = w2r[o],      w1 = w2r[8 + o];   // SGPR, x4 reuse
                const float2v w2_ = w2r[16 + o], w3_ = w2r[24 + o];
                #pragma unroll
                for (int qq = 0; qq < 4; ++qq) {
                    acc[qq][o] += h01[qq].x * w0;
                    acc[qq][o] += h01[qq].y * w1;
                    acc[qq][o] += h23[qq].x * w2_;
                    acc[qq][o] += h23[qq].y * w3_;
                }
            }
        }
        kva = nka; kvb = nkb;
    }

    // layer 3 + bias -> logits (4 per thread)
    float logit[4];
    #pragma unroll
    for (int qq = 0; qq < 4; ++qq) {
        float a = b3[0];
        #pragma unroll
        for (int o = 0; o < 8; ++o) {
            a = fmaf(fmaxf(acc[qq][o].x, 0.f), W3[2 * o], a);
            a = fmaf(fmaxf(acc[qq][o].y, 0.f), W3[2 * o + 1], a);
        }
        logit[qq] = fmaf(fmaxf(a, 0.f), pmv[qq], pav[qq]);
    }

    // ---- softmax for 4 queries (logits in-register) ----
    float m[4] = {logit[0], logit[1], logit[2], logit[3]};
    #pragma unroll
    for (int off = 32; off > 0; off >>= 1)
        #pragma unroll
        for (int qq = 0; qq < 4; ++qq) m[qq] = fmaxf(m[qq], __shfl_xor(m[qq], off));
    if (lane == 0)
        #pragma unroll
        for (int qq = 0; qq < 4; ++qq) redm[qq][wv] = m[qq];
    __syncthreads();
    float e[4], s[4];
    #pragma unroll
    for (int qq = 0; qq < 4; ++qq) {
        float M = redm[qq][0];
        #pragma unroll
        for (int w = 1; w < 8; ++w) M = fmaxf(M, redm[qq][w]);
        e[qq] = __expf(logit[qq] - M);
        s[qq] = e[qq];
    }
    *reinterpret_cast<float4*>(&sc4[t][0]) =
        float4{e[0], e[1], e[2], e[3]};                  // ds_write_b128
    #pragma unroll
    for (int off = 32; off > 0; off >>= 1)
        #pragma unroll
        for (int qq = 0; qq < 4; ++qq) s[qq] += __shfl_xor(s[qq], off);
    if (lane == 0)
        #pragma unroll
        for (int qq = 0; qq < 4; ++qq) reds[qq][wv] = s[qq];
    __syncthreads();
    float inv[4];
    #pragma unroll
    for (int qq = 0; qq < 4; ++qq) {
        float S = 0.f;
        #pragma unroll
        for (int w = 0; w < 8; ++w) S += reds[qq][w];
        inv[qq] = 1.f / S;
    }

    // ---- A@V: wave wv covers keys wv*64..+63; lane = dim. V load shared x4;
    //      score read is wave-uniform (LDS broadcast, free). ----
    const float* vbase = Vp + (((size_t)(b * SQ + wv * 64)) * NGQ + g) * DGQ + lane;
    float2v av01 = {0.f, 0.f}, av23 = {0.f, 0.f};
    #pragma unroll 8
    for (int k = 0; k < 64; ++k) {
        const float v = vbase[(size_t)k * (NGQ * DGQ)];
        const float4 sv = *reinterpret_cast<const float4*>(&sc4[wv * 64 + k][0]);
        av01 += v * float2v{sv.x, sv.y};
        av23 += v * float2v{sv.z, sv.w};
    }
    avs[0][wv][lane] = av01.x; avs[1][wv][lane] = av01.y;
    avs[2][wv][lane] = av23.x; avs[3][wv][lane] = av23.y;
    __syncthreads();
    if (t < 4 * DGQ) {
        const int qq = t >> 6, d = t & 63;
        float sum = 0.f;
        #pragma unroll
        for (int w = 0; w < 8; ++w) sum += avs[qq][w][d];
        out[((size_t)(b * SQ + i0 + qq)) * DQ + d * NGQ + g] = sum * inv[qq];
    }
}

extern "C" void kernel_launch(void* const* d_in, const int* in_sizes, int n_in,
                              void* d_out, int out_size, void* d_ws, size_t ws_size,
                              hipStream_t stream) {
    const float* x       = (const float*)d_in[0];
    const float* pos_add = (const float*)d_in[1];
    const float* pos_mul = (const float*)d_in[2];
    const float* Wq      = (const float*)d_in[3];
    const float* Wk      = (const float*)d_in[4];
    const float* Wv      = (const float*)d_in[5];
    const float* W1      = (const float*)d_in[6];
    const float* b1      = (const float*)d_in[7];
    const float* W2      = (const float*)d_in[8];
    const float* b2      = (const float*)d_in[9];
    const float* W3      = (const float*)d_in[10];
    const float* b3      = (const float*)d_in[11];
    float* out = (float*)d_out;

    float* ws  = (float*)d_ws;
    float* QW1 = ws;
    float* KW1 = ws + 131072;
    float* Vp  = ws + 262144;

    proj_kernel<<<BQ * SQ, 256, 0, stream>>>(x, Wq, Wk, Wv, W1, b1,
                                             QW1, KW1, Vp);
    attn_kernel<<<BQ * NGQ * SQ / 4, 512, 0, stream>>>(QW1, KW1, Vp, W2, b2,
                                                       W3, b3, pos_add, pos_mul,
                                                       out);
}